// Round 1
// baseline (831.604 us; speedup 1.0000x reference)
//
#include <hip/hip_runtime.h>
#include <cstdint>

typedef unsigned long long u64;
typedef uint32_t u32;

#define NB 2048

// ---------------------------------------------------------------------------
// Faithful f32 replication of the reference geometry. contract(off) so we
// match XLA's separate mul/add rounding (no fma contraction).
// ---------------------------------------------------------------------------

__device__ __forceinline__ bool pt_in(float px, float py, float cx, float cy,
                                      float hw, float hh, float c, float s) {
#pragma clang fp contract(off)
  float ax = px - cx;
  float ay = py - cy;
  float lx = c * ax + s * ay;
  float ly = c * ay - s * ax;   // == (-s)*ax + (c*ay), bitwise identical
  return (fabsf(lx) <= hw + 1e-5f) && (fabsf(ly) <= hh + 1e-5f);
}

__device__ float pair_inter_area(float acx, float acy, float aw, float ah,
                                 float ac, float as_, float bcx, float bcy,
                                 float bw, float bh, float bc, float bs_) {
#pragma clang fp contract(off)
  const float SX[4] = {-1.f, 1.f, 1.f, -1.f};
  const float SY[4] = {-1.f, -1.f, 1.f, 1.f};
  float axx[4], ayy[4], bxx[4], byy[4];
  float ahw = aw * 0.5f, ahh = ah * 0.5f;
  float bhw = bw * 0.5f, bhh = bh * 0.5f;
#pragma unroll
  for (int q = 0; q < 4; ++q) {
    float dx = SX[q] * ahw, dy = SY[q] * ahh;
    axx[q] = acx + ac * dx - as_ * dy;
    ayy[q] = acy + as_ * dx + ac * dy;
    float ex = SX[q] * bhw, ey = SY[q] * bhh;
    bxx[q] = bcx + bc * ex - bs_ * ey;
    byy[q] = bcy + bs_ * ex + bc * ey;
  }
  float px_[24], py_[24];
  bool mk[24];
#pragma unroll
  for (int q = 0; q < 4; ++q) {
    px_[q] = axx[q]; py_[q] = ayy[q];
    mk[q] = pt_in(axx[q], ayy[q], bcx, bcy, bhw, bhh, bc, bs_);
    px_[4 + q] = bxx[q]; py_[4 + q] = byy[q];
    mk[4 + q] = pt_in(bxx[q], byy[q], acx, acy, ahw, ahh, ac, as_);
  }
#pragma unroll
  for (int e = 0; e < 4; ++e) {
    float rx = axx[(e + 1) & 3] - axx[e];
    float ry = ayy[(e + 1) & 3] - ayy[e];
#pragma unroll
    for (int f = 0; f < 4; ++f) {
      float sx = bxx[(f + 1) & 3] - bxx[f];
      float sy = byy[(f + 1) & 3] - byy[f];
      float denom = rx * sy - ry * sx;
      float qpx = bxx[f] - axx[e];
      float qpy = byy[f] - ayy[e];
      bool dn = fabsf(denom) > 1e-9f;
      float safe = dn ? denom : 1.0f;
      float t = (qpx * sy - qpy * sx) / safe;
      float uu = (qpx * ry - qpy * rx) / safe;
      bool valid = dn && (t >= 0.0f) && (t <= 1.0f) && (uu >= 0.0f) && (uu <= 1.0f);
      int id = 8 + e * 4 + f;
      px_[id] = axx[e] + t * rx;
      py_[id] = ayy[e] + t * ry;
      mk[id] = valid;
    }
  }
  int k = 0;
  float sx0 = 0.0f, sy0 = 0.0f;
#pragma unroll
  for (int q = 0; q < 24; ++q) {
    if (mk[q]) { k++; sx0 += px_[q]; sy0 += py_[q]; }
  }
  float kk = (float)(k > 0 ? k : 1);
  float cxm = sx0 / kk, cym = sy0 / kk;
  // angle keys: order-preserving int map of f32 angle, index tiebreak
  // replicates jnp's stable argsort exactly.
  u64 key[24];
  float dxr[24], dyr[24];
#pragma unroll
  for (int q = 0; q < 24; ++q) {
    float dx = px_[q] - cxm, dy = py_[q] - cym;
    dxr[q] = dx; dyr[q] = dy;
    float ang = mk[q] ? atan2f(dy, dx) : 1e9f;
    u32 ub = __float_as_uint(ang);
    u32 v = (ub & 0x80000000u) ? ~ub : (ub | 0x80000000u);
    key[q] = (((u64)v) << 5) | (u64)q;
  }
  for (int a = 1; a < 24; ++a) {
    u64 kv = key[a];
    float dx = dxr[a], dy = dyr[a];
    int b = a - 1;
    while (b >= 0 && key[b] > kv) {
      key[b + 1] = key[b]; dxr[b + 1] = dxr[b]; dyr[b + 1] = dyr[b];
      --b;
    }
    key[b + 1] = kv; dxr[b + 1] = dx; dyr[b + 1] = dy;
  }
  float acc = 0.0f;
  for (int q = 0; q < 24; ++q) {
    if (q < k) {
      int n2 = (q + 1 < k) ? q + 1 : 0;
      acc += dxr[q] * dyr[n2] - dyr[q] * dxr[n2];
    }
  }
  float area = 0.5f * fabsf(acc);
  return (k >= 3) ? area : 0.0f;
}

// ---------------------------------------------------------------------------
// K1: offset_scale = (max(max cx, max cy) + 0.5*max sqrt(w^2+h^2))*2 + 1
// ---------------------------------------------------------------------------
__global__ __launch_bounds__(256) void reduce_kernel(const float* __restrict__ boxes,
                                                     float* __restrict__ osc) {
#pragma clang fp contract(off)
  __shared__ float smc[4], smr[4];
  int t = threadIdx.x;
  float mc = -1e30f, mr = -1e30f;
  for (int i = t; i < NB; i += 256) {
    float cx = boxes[i * 5 + 0];
    float cy = boxes[i * 5 + 1];
    float w = boxes[i * 5 + 2];
    float h = boxes[i * 5 + 3];
    mc = fmaxf(mc, fmaxf(cx, cy));
    float ww = w * w;
    float hh = h * h;
    mr = fmaxf(mr, sqrtf(ww + hh));
  }
  for (int off = 32; off > 0; off >>= 1) {
    mc = fmaxf(mc, __shfl_down(mc, off));
    mr = fmaxf(mr, __shfl_down(mr, off));
  }
  if ((t & 63) == 0) { smc[t >> 6] = mc; smr[t >> 6] = mr; }
  __syncthreads();
  if (t == 0) {
    mc = fmaxf(fmaxf(smc[0], smc[1]), fmaxf(smc[2], smc[3]));
    mr = fmaxf(fmaxf(smr[0], smr[1]), fmaxf(smr[2], smr[3]));
    float max_radius = mr * 0.5f;
    *osc = (mc + max_radius) * 2.0f + 1.0f;
  }
}

// ---------------------------------------------------------------------------
// K2: stable rank (== stable argsort(-scores)) + sorted SoA with class offsets
// ---------------------------------------------------------------------------
__global__ __launch_bounds__(256) void build_kernel(
    const float* __restrict__ boxes, const float* __restrict__ scores,
    const int* __restrict__ labels, const float* __restrict__ osc,
    float* __restrict__ cxp, float* __restrict__ cyp, float* __restrict__ wp,
    float* __restrict__ hp, float* __restrict__ cp, float* __restrict__ sp,
    float* __restrict__ radp, float* __restrict__ sscp, int* __restrict__ sidx) {
#pragma clang fp contract(off)
  __shared__ float sc[NB];
  int t = threadIdx.x;
  int i = blockIdx.x * 256 + t;
  for (int j = t; j < NB; j += 256) sc[j] = scores[j];
  __syncthreads();
  float si = scores[i];
  int rank = 0;
#pragma unroll 8
  for (int j = 0; j < NB; ++j) {
    float sj = sc[j];
    rank += (int)((sj > si) || (sj == si && j < i));
  }
  float off = (float)labels[i] * (*osc);
  float cx = boxes[i * 5 + 0] + off;
  float cy = boxes[i * 5 + 1] + off;
  float w = boxes[i * 5 + 2];
  float h = boxes[i * 5 + 3];
  float a = boxes[i * 5 + 4];
  float c = cosf(a);
  float s = sinf(a);
  float ww = w * w;
  float hh = h * h;
  cxp[rank] = cx;
  cyp[rank] = cy;
  wp[rank] = w;
  hp[rank] = h;
  cp[rank] = c;
  sp[rank] = s;
  radp[rank] = 0.5f * sqrtf(ww + hh);
  sscp[rank] = si;
  sidx[rank] = i;
}

// ---------------------------------------------------------------------------
// K3: suppression bitmask. One wave per 64 j's of row i; circle pre-reject.
// ---------------------------------------------------------------------------
__global__ __launch_bounds__(256) void pair_kernel(
    const float* __restrict__ cxp, const float* __restrict__ cyp,
    const float* __restrict__ wp, const float* __restrict__ hp,
    const float* __restrict__ cp, const float* __restrict__ sp,
    const float* __restrict__ radp, const float* __restrict__ thrp,
    u64* __restrict__ mask) {
#pragma clang fp contract(off)
  int i = blockIdx.y;
  int j = blockIdx.x * 256 + threadIdx.x;
  float thr = *thrp;
  float acx = cxp[i], acy = cyp[i], arad = radp[i];
  bool bit = false;
  if (j > i) {
    float bcx = cxp[j], bcy = cyp[j], brad = radp[j];
    float dx = bcx - acx, dy = bcy - acy;
    float rr = arad + brad + 1.0f;   // conservative: IoU>0 needs circle overlap
    if (dx * dx + dy * dy <= rr * rr) {
      float aw = wp[i], ah = hp[i], ac = cp[i], as_ = sp[i];
      float bw = wp[j], bh = hp[j], bc = cp[j], bs_ = sp[j];
      float inter = pair_inter_area(acx, acy, aw, ah, ac, as_,
                                    bcx, bcy, bw, bh, bc, bs_);
      float areaA = aw * ah;
      float areaB = bw * bh;
      float iou = inter / (areaA + areaB - inter + 1e-9f);
      bit = iou > thr;
    }
  }
  u64 word = __ballot(bit);
  if ((threadIdx.x & 63) == 0) mask[(size_t)i * 32 + (j >> 6)] = word;
}

// ---------------------------------------------------------------------------
// K4: sequential greedy scan, single wave. Lanes 0..31 own alive words.
// Rows prefetched depth-8 (both the lane word and the broadcast intra-word
// word), so the per-i chain is register-only bit tests.
// ---------------------------------------------------------------------------
__global__ __launch_bounds__(64) void greedy_kernel(const u64* __restrict__ mask,
                                                    u64* __restrict__ alive_out) {
  int lane = threadIdx.x;
  u64 alive = ~0ull;
  u64 bufm[8], bufs[8];
#pragma unroll
  for (int d = 0; d < 8; ++d) {
    bufm[d] = (lane < 32) ? mask[d * 32 + lane] : 0ull;
    bufs[d] = mask[d * 32 + 0];   // word (d>>6)==0 for d<8
  }
  u64 aw = 0;
  for (int i0 = 0; i0 < NB; i0 += 8) {
#pragma unroll
    for (int d = 0; d < 8; ++d) {
      int i = i0 + d;
      u64 m = bufm[d];
      u64 mv = bufs[d];
      int nf = i + 8;
      if (nf < NB) {
        bufm[d] = (lane < 32) ? mask[(size_t)nf * 32 + lane] : 0ull;
        bufs[d] = mask[(size_t)nf * 32 + (nf >> 6)];
      }
      int w = i >> 6, b = i & 63;
      if (b == 0) aw = __shfl(alive, w);
      if ((aw >> b) & 1ull) {
        aw &= ~mv;      // track kills within current word
        alive &= ~m;    // kill in owned word
      }
    }
  }
  if (lane < 32) alive_out[lane] = alive;
}

// ---------------------------------------------------------------------------
// K5: scatter output: out[orig] = score * keep
// ---------------------------------------------------------------------------
__global__ __launch_bounds__(256) void output_kernel(const u64* __restrict__ alive,
                                                     const float* __restrict__ sscp,
                                                     const int* __restrict__ sidx,
                                                     float* __restrict__ out) {
  int p = blockIdx.x * 256 + threadIdx.x;
  int bit = (int)((alive[p >> 6] >> (p & 63)) & 1ull);
  out[sidx[p]] = bit ? sscp[p] : 0.0f;
}

extern "C" void kernel_launch(void* const* d_in, const int* in_sizes, int n_in,
                              void* d_out, int out_size, void* d_ws, size_t ws_size,
                              hipStream_t stream) {
  const float* boxes = (const float*)d_in[0];
  const float* scores = (const float*)d_in[1];
  const int* labels = (const int*)d_in[2];
  const float* thr = (const float*)d_in[3];
  float* out = (float*)d_out;

  char* base = (char*)d_ws;
  float* osc = (float*)base;                 // 4 B
  float* arr = (float*)(base + 256);         // 8 SoA arrays of 2048 f32
  float* cxp = arr + 0 * NB;
  float* cyp = arr + 1 * NB;
  float* wp = arr + 2 * NB;
  float* hp = arr + 3 * NB;
  float* cp = arr + 4 * NB;
  float* sp = arr + 5 * NB;
  float* radp = arr + 6 * NB;
  float* sscp = arr + 7 * NB;
  int* sidx = (int*)(base + 256 + 8 * NB * 4);
  u64* mask = (u64*)(base + 131072);                 // 2048*32 u64 = 512 KB
  u64* alive = (u64*)(base + 131072 + (size_t)NB * 32 * 8);

  reduce_kernel<<<1, 256, 0, stream>>>(boxes, osc);
  build_kernel<<<8, 256, 0, stream>>>(boxes, scores, labels, osc, cxp, cyp, wp,
                                      hp, cp, sp, radp, sscp, sidx);
  pair_kernel<<<dim3(8, NB), 256, 0, stream>>>(cxp, cyp, wp, hp, cp, sp, radp,
                                               thr, mask);
  greedy_kernel<<<1, 64, 0, stream>>>(mask, alive);
  output_kernel<<<8, 256, 0, stream>>>(alive, sscp, sidx, out);
}

// Round 2
// 204.821 us; speedup vs baseline: 4.0602x; 4.0602x over previous
//
#include <hip/hip_runtime.h>
#include <cstdint>

typedef unsigned long long u64;
typedef uint32_t u32;

#define NB 2048

// ---------------------------------------------------------------------------
// Faithful f32 replication of the reference geometry. contract(off) so we
// match XLA's separate mul/add rounding (no fma contraction).
// ---------------------------------------------------------------------------

__device__ __forceinline__ bool pt_in(float px, float py, float cx, float cy,
                                      float hw, float hh, float c, float s) {
#pragma clang fp contract(off)
  float ax = px - cx;
  float ay = py - cy;
  float lx = c * ax + s * ay;
  float ly = c * ay - s * ax;   // == (-s)*ax + (c*ay), bitwise identical
  return (fabsf(lx) <= hw + 1e-5f) && (fabsf(ly) <= hh + 1e-5f);
}

__device__ float pair_inter_area(float acx, float acy, float aw, float ah,
                                 float ac, float as_, float bcx, float bcy,
                                 float bw, float bh, float bc, float bs_) {
#pragma clang fp contract(off)
  const float SX[4] = {-1.f, 1.f, 1.f, -1.f};
  const float SY[4] = {-1.f, -1.f, 1.f, 1.f};
  float axx[4], ayy[4], bxx[4], byy[4];
  float ahw = aw * 0.5f, ahh = ah * 0.5f;
  float bhw = bw * 0.5f, bhh = bh * 0.5f;
#pragma unroll
  for (int q = 0; q < 4; ++q) {
    float dx = SX[q] * ahw, dy = SY[q] * ahh;
    axx[q] = acx + ac * dx - as_ * dy;
    ayy[q] = acy + as_ * dx + ac * dy;
    float ex = SX[q] * bhw, ey = SY[q] * bhh;
    bxx[q] = bcx + bc * ex - bs_ * ey;
    byy[q] = bcy + bs_ * ex + bc * ey;
  }
  float px_[24], py_[24];
  bool mk[24];
#pragma unroll
  for (int q = 0; q < 4; ++q) {
    px_[q] = axx[q]; py_[q] = ayy[q];
    mk[q] = pt_in(axx[q], ayy[q], bcx, bcy, bhw, bhh, bc, bs_);
    px_[4 + q] = bxx[q]; py_[4 + q] = byy[q];
    mk[4 + q] = pt_in(bxx[q], byy[q], acx, acy, ahw, ahh, ac, as_);
  }
#pragma unroll
  for (int e = 0; e < 4; ++e) {
    float rx = axx[(e + 1) & 3] - axx[e];
    float ry = ayy[(e + 1) & 3] - ayy[e];
#pragma unroll
    for (int f = 0; f < 4; ++f) {
      float sx = bxx[(f + 1) & 3] - bxx[f];
      float sy = byy[(f + 1) & 3] - byy[f];
      float denom = rx * sy - ry * sx;
      float qpx = bxx[f] - axx[e];
      float qpy = byy[f] - ayy[e];
      bool dn = fabsf(denom) > 1e-9f;
      float safe = dn ? denom : 1.0f;
      float t = (qpx * sy - qpy * sx) / safe;
      float uu = (qpx * ry - qpy * rx) / safe;
      bool valid = dn && (t >= 0.0f) && (t <= 1.0f) && (uu >= 0.0f) && (uu <= 1.0f);
      int id = 8 + e * 4 + f;
      px_[id] = axx[e] + t * rx;
      py_[id] = ayy[e] + t * ry;
      mk[id] = valid;
    }
  }
  int k = 0;
  float sx0 = 0.0f, sy0 = 0.0f;
#pragma unroll
  for (int q = 0; q < 24; ++q) {
    if (mk[q]) { k++; sx0 += px_[q]; sy0 += py_[q]; }
  }
  float kk = (float)(k > 0 ? k : 1);
  float cxm = sx0 / kk, cym = sy0 / kk;
  u64 key[24];
  float dxr[24], dyr[24];
#pragma unroll
  for (int q = 0; q < 24; ++q) {
    float dx = px_[q] - cxm, dy = py_[q] - cym;
    dxr[q] = dx; dyr[q] = dy;
    float ang = mk[q] ? atan2f(dy, dx) : 1e9f;
    u32 ub = __float_as_uint(ang);
    u32 v = (ub & 0x80000000u) ? ~ub : (ub | 0x80000000u);
    key[q] = (((u64)v) << 5) | (u64)q;
  }
  for (int a = 1; a < 24; ++a) {
    u64 kv = key[a];
    float dx = dxr[a], dy = dyr[a];
    int b = a - 1;
    while (b >= 0 && key[b] > kv) {
      key[b + 1] = key[b]; dxr[b + 1] = dxr[b]; dyr[b + 1] = dyr[b];
      --b;
    }
    key[b + 1] = kv; dxr[b + 1] = dx; dyr[b + 1] = dy;
  }
  float acc = 0.0f;
  for (int q = 0; q < 24; ++q) {
    if (q < k) {
      int n2 = (q + 1 < k) ? q + 1 : 0;
      acc += dxr[q] * dyr[n2] - dyr[q] * dxr[n2];
    }
  }
  float area = 0.5f * fabsf(acc);
  return (k >= 3) ? area : 0.0f;
}

// ---------------------------------------------------------------------------
// K1: offset_scale reduction
// ---------------------------------------------------------------------------
__global__ __launch_bounds__(256) void reduce_kernel(const float* __restrict__ boxes,
                                                     float* __restrict__ osc) {
#pragma clang fp contract(off)
  __shared__ float smc[4], smr[4];
  int t = threadIdx.x;
  float mc = -1e30f, mr = -1e30f;
  for (int i = t; i < NB; i += 256) {
    float cx = boxes[i * 5 + 0];
    float cy = boxes[i * 5 + 1];
    float w = boxes[i * 5 + 2];
    float h = boxes[i * 5 + 3];
    mc = fmaxf(mc, fmaxf(cx, cy));
    float ww = w * w;
    float hh = h * h;
    mr = fmaxf(mr, sqrtf(ww + hh));
  }
  for (int off = 32; off > 0; off >>= 1) {
    mc = fmaxf(mc, __shfl_down(mc, off));
    mr = fmaxf(mr, __shfl_down(mr, off));
  }
  if ((t & 63) == 0) { smc[t >> 6] = mc; smr[t >> 6] = mr; }
  __syncthreads();
  if (t == 0) {
    mc = fmaxf(fmaxf(smc[0], smc[1]), fmaxf(smc[2], smc[3]));
    mr = fmaxf(fmaxf(smr[0], smr[1]), fmaxf(smr[2], smr[3]));
    float max_radius = mr * 0.5f;
    *osc = (mc + max_radius) * 2.0f + 1.0f;
  }
}

// ---------------------------------------------------------------------------
// K2: stable rank sort + sorted SoA; also zeros the nz bitmap.
// ---------------------------------------------------------------------------
__global__ __launch_bounds__(256) void build_kernel(
    const float* __restrict__ boxes, const float* __restrict__ scores,
    const int* __restrict__ labels, const float* __restrict__ osc,
    float* __restrict__ cxp, float* __restrict__ cyp, float* __restrict__ wp,
    float* __restrict__ hp, float* __restrict__ cp, float* __restrict__ sp,
    float* __restrict__ radp, float* __restrict__ sscp, int* __restrict__ sidx,
    u32* __restrict__ nzmask) {
#pragma clang fp contract(off)
  __shared__ float sc[NB];
  int t = threadIdx.x;
  int i = blockIdx.x * 256 + t;
  nzmask[i] = 0u;
  for (int j = t; j < NB; j += 256) sc[j] = scores[j];
  __syncthreads();
  float si = scores[i];
  int rank = 0;
#pragma unroll 8
  for (int j = 0; j < NB; ++j) {
    float sj = sc[j];
    rank += (int)((sj > si) || (sj == si && j < i));
  }
  float off = (float)labels[i] * (*osc);
  float cx = boxes[i * 5 + 0] + off;
  float cy = boxes[i * 5 + 1] + off;
  float w = boxes[i * 5 + 2];
  float h = boxes[i * 5 + 3];
  float a = boxes[i * 5 + 4];
  float c = cosf(a);
  float s = sinf(a);
  float ww = w * w;
  float hh = h * h;
  cxp[rank] = cx;
  cyp[rank] = cy;
  wp[rank] = w;
  hp[rank] = h;
  cp[rank] = c;
  sp[rank] = s;
  radp[rank] = 0.5f * sqrtf(ww + hh);
  sscp[rank] = si;
  sidx[rank] = i;
}

// ---------------------------------------------------------------------------
// K3: suppression bitmask + per-row nonzero-word bitmap.
// ---------------------------------------------------------------------------
__global__ __launch_bounds__(256) void pair_kernel(
    const float* __restrict__ cxp, const float* __restrict__ cyp,
    const float* __restrict__ wp, const float* __restrict__ hp,
    const float* __restrict__ cp, const float* __restrict__ sp,
    const float* __restrict__ radp, const float* __restrict__ thrp,
    u64* __restrict__ mask, u32* __restrict__ nzmask) {
#pragma clang fp contract(off)
  int i = blockIdx.y;
  int j = blockIdx.x * 256 + threadIdx.x;
  float thr = *thrp;
  float acx = cxp[i], acy = cyp[i], arad = radp[i];
  bool bit = false;
  if (j > i) {
    float bcx = cxp[j], bcy = cyp[j], brad = radp[j];
    float dx = bcx - acx, dy = bcy - acy;
    float rr = arad + brad + 1.0f;   // conservative: IoU>0 needs circle overlap
    if (dx * dx + dy * dy <= rr * rr) {
      float aw = wp[i], ah = hp[i], ac = cp[i], as_ = sp[i];
      float bw = wp[j], bh = hp[j], bc = cp[j], bs_ = sp[j];
      float inter = pair_inter_area(acx, acy, aw, ah, ac, as_,
                                    bcx, bcy, bw, bh, bc, bs_);
      float areaA = aw * ah;
      float areaB = bw * bh;
      float iou = inter / (areaA + areaB - inter + 1e-9f);
      bit = iou > thr;
    }
  }
  u64 word = __ballot(bit);
  if ((threadIdx.x & 63) == 0) {
    int wi = j >> 6;
    mask[(size_t)i * 32 + wi] = word;
    if (word) atomicOr(&nzmask[i], 1u << wi);
  }
}

// ---------------------------------------------------------------------------
// K4: greedy keep as parallel fixpoint iteration (antitone F, converges to
// the exact sequential-greedy fixpoint in chain-depth+2 iterations).
// Only nonzero mask words (per nzmask) are touched each iteration.
// ---------------------------------------------------------------------------
__global__ __launch_bounds__(256) void greedy_kernel(const u64* __restrict__ mask,
                                                     const u32* __restrict__ nzmask,
                                                     u64* __restrict__ alive_out) {
  __shared__ u64 keepw[32];
  __shared__ u32 Sw32[64];          // 32 u64 words as 64 u32 halves
  __shared__ u32 nzrows[NB];
  __shared__ u32 nzm[NB];
  __shared__ int nzcnt;
  __shared__ int changed;
  int t = threadIdx.x;
  if (t == 0) nzcnt = 0;
  if (t < 32) keepw[t] = ~0ull;
  __syncthreads();
  for (int i = t; i < NB; i += 256) {
    u32 b = nzmask[i];
    nzm[i] = b;
    if (b) { int s = atomicAdd(&nzcnt, 1); nzrows[s] = (u32)i; }
  }
  __syncthreads();
  int cnt = nzcnt;
  for (int iter = 0; iter < 2060; ++iter) {
    if (t < 64) Sw32[t] = 0u;
    if (t == 0) changed = 0;
    __syncthreads();
    for (int r = t; r < cnt; r += 256) {
      u32 i = nzrows[r];
      if ((keepw[i >> 6] >> (i & 63)) & 1ull) {
        u32 b = nzm[i];
        while (b) {
          int w = __builtin_ctz(b);
          b &= b - 1;
          u64 m = mask[(size_t)i * 32 + w];
          u32 lo = (u32)m, hi = (u32)(m >> 32);
          if (lo) atomicOr(&Sw32[2 * w], lo);
          if (hi) atomicOr(&Sw32[2 * w + 1], hi);
        }
      }
    }
    __syncthreads();
    if (t < 32) {
      u64 S = ((u64)Sw32[2 * t]) | (((u64)Sw32[2 * t + 1]) << 32);
      u64 nk = ~S;
      if (nk != keepw[t]) { keepw[t] = nk; changed = 1; }
    }
    __syncthreads();
    int ch = changed;
    __syncthreads();   // everyone reads `changed` before next iter overwrites
    if (!ch) break;
  }
  if (t < 32) alive_out[t] = keepw[t];
}

// ---------------------------------------------------------------------------
// K5: scatter output: out[orig] = score * keep
// ---------------------------------------------------------------------------
__global__ __launch_bounds__(256) void output_kernel(const u64* __restrict__ alive,
                                                     const float* __restrict__ sscp,
                                                     const int* __restrict__ sidx,
                                                     float* __restrict__ out) {
  int p = blockIdx.x * 256 + threadIdx.x;
  int bit = (int)((alive[p >> 6] >> (p & 63)) & 1ull);
  out[sidx[p]] = bit ? sscp[p] : 0.0f;
}

extern "C" void kernel_launch(void* const* d_in, const int* in_sizes, int n_in,
                              void* d_out, int out_size, void* d_ws, size_t ws_size,
                              hipStream_t stream) {
  const float* boxes = (const float*)d_in[0];
  const float* scores = (const float*)d_in[1];
  const int* labels = (const int*)d_in[2];
  const float* thr = (const float*)d_in[3];
  float* out = (float*)d_out;

  char* base = (char*)d_ws;
  float* osc = (float*)base;                  // 4 B
  float* arr = (float*)(base + 256);          // 8 SoA arrays of 2048 f32 (64 KB)
  float* cxp = arr + 0 * NB;
  float* cyp = arr + 1 * NB;
  float* wp = arr + 2 * NB;
  float* hp = arr + 3 * NB;
  float* cp = arr + 4 * NB;
  float* sp = arr + 5 * NB;
  float* radp = arr + 6 * NB;
  float* sscp = arr + 7 * NB;
  int* sidx = (int*)(base + 256 + 8 * NB * 4);      // 8 KB, ends 73984
  u32* nzmask = (u32*)(base + 81920);               // 8 KB, ends 90112
  u64* mask = (u64*)(base + 131072);                // 2048*32 u64 = 512 KB
  u64* alive = (u64*)(base + 131072 + (size_t)NB * 32 * 8);  // 256 B

  reduce_kernel<<<1, 256, 0, stream>>>(boxes, osc);
  build_kernel<<<8, 256, 0, stream>>>(boxes, scores, labels, osc, cxp, cyp, wp,
                                      hp, cp, sp, radp, sscp, sidx, nzmask);
  pair_kernel<<<dim3(8, NB), 256, 0, stream>>>(cxp, cyp, wp, hp, cp, sp, radp,
                                               thr, mask, nzmask);
  greedy_kernel<<<1, 256, 0, stream>>>(mask, nzmask, alive);
  output_kernel<<<8, 256, 0, stream>>>(alive, sscp, sidx, out);
}